// Round 1
// baseline (43802.231 us; speedup 1.0000x reference)
//
#include <hip/hip_runtime.h>

#define BB 64
#define CXC 16
#define CYC 64
#define LL 32
#define MM 28
#define NN 1024
#define SP (MM*MM)          // 784
#define KTOT (CYC*SP)       // 50176
#define NSTEPS 50

// ---------------- GEMM1: zpart[cy][b][n] = f[b, cy*784 .. ] @ W[n, cy*784 ..]^T ----------------
// grid (16 n-tiles, 64 cy-splits), block 256. 64x64 tile, 4x4 per thread, KB=16.
__global__ __launch_bounds__(256) void gemm1_kernel(const float* __restrict__ f,
                                                    const float* __restrict__ W,
                                                    float* __restrict__ zpart) {
    const int nt  = blockIdx.x;   // 0..15
    const int cy  = blockIdx.y;   // 0..63
    const int tid = threadIdx.x;
    const int tx = tid & 15, ty = tid >> 4;
    __shared__ float fs[16][64];
    __shared__ float ws[16][64];
    float acc[4][4];
#pragma unroll
    for (int i = 0; i < 4; i++)
#pragma unroll
        for (int j = 0; j < 4; j++) acc[i][j] = 0.f;

    const int n0  = nt * 64;
    const int ldb = tid >> 2;          // 0..63 : b for fs, local n for ws
    const int kg  = (tid & 3) << 2;    // 0,4,8,12
    const float* fp = f + ldb * KTOT + cy * SP + kg;
    const float* wp = W + (n0 + ldb) * KTOT + cy * SP + kg;

    for (int k0 = 0; k0 < SP; k0 += 16) {
        float4 fv = *(const float4*)(fp + k0);
        float4 wv = *(const float4*)(wp + k0);
        __syncthreads();
        fs[kg + 0][ldb] = fv.x; fs[kg + 1][ldb] = fv.y;
        fs[kg + 2][ldb] = fv.z; fs[kg + 3][ldb] = fv.w;
        ws[kg + 0][ldb] = wv.x; ws[kg + 1][ldb] = wv.y;
        ws[kg + 2][ldb] = wv.z; ws[kg + 3][ldb] = wv.w;
        __syncthreads();
#pragma unroll
        for (int kk = 0; kk < 16; kk++) {
            float4 fb = *(const float4*)&fs[kk][ty << 2];
            float4 wb = *(const float4*)&ws[kk][tx << 2];
            float fa[4] = {fb.x, fb.y, fb.z, fb.w};
            float wa[4] = {wb.x, wb.y, wb.z, wb.w};
#pragma unroll
            for (int i = 0; i < 4; i++)
#pragma unroll
                for (int j = 0; j < 4; j++) acc[i][j] += fa[i] * wa[j];
        }
    }
#pragma unroll
    for (int i = 0; i < 4; i++)
#pragma unroll
        for (int j = 0; j < 4; j++)
            zpart[cy * (BB * NN) + (ty * 4 + i) * NN + n0 + tx * 4 + j] = acc[i][j];
}

// ---------------- reduce zpart over cy + row softmax -> g ----------------
__global__ __launch_bounds__(256) void softmax_g_kernel(const float* __restrict__ zpart,
                                                        float* __restrict__ g) {
    const int b = blockIdx.x, tid = threadIdx.x;
    float zv[4];
#pragma unroll
    for (int q = 0; q < 4; q++) {
        const int n = tid + q * 256;
        float s = 0.f;
#pragma unroll 4
        for (int cy = 0; cy < 64; cy++) s += zpart[cy * (BB * NN) + b * NN + n];
        zv[q] = s;
    }
    __shared__ float red[8];
    float m = fmaxf(fmaxf(zv[0], zv[1]), fmaxf(zv[2], zv[3]));
#pragma unroll
    for (int off = 32; off > 0; off >>= 1) m = fmaxf(m, __shfl_down(m, off));
    if ((tid & 63) == 0) red[tid >> 6] = m;
    __syncthreads();
    const float bm = fmaxf(fmaxf(red[0], red[1]), fmaxf(red[2], red[3]));
    float e[4];
    float ssum = 0.f;
#pragma unroll
    for (int q = 0; q < 4; q++) { e[q] = __expf(zv[q] - bm); ssum += e[q]; }
#pragma unroll
    for (int off = 32; off > 0; off >>= 1) ssum += __shfl_down(ssum, off);
    if ((tid & 63) == 0) red[4 + (tid >> 6)] = ssum;
    __syncthreads();
    const float inv = 1.0f / (red[4] + red[5] + red[6] + red[7]);
#pragma unroll
    for (int q = 0; q < 4; q++) g[b * NN + tid + q * 256] = e[q] * inv;
}

// ---------------- GEMM2: y[b][k] = sum_n g[b][n] * W[n][k] ----------------
// grid 392 k-tiles (128 wide), block 256. 64x128 tile, 4x8 per thread, NB=32.
__global__ __launch_bounds__(256) void gemm2_kernel(const float* __restrict__ g,
                                                    const float* __restrict__ W,
                                                    float* __restrict__ y) {
    const int kt  = blockIdx.x;   // 0..391
    const int tid = threadIdx.x;
    const int tx = tid & 15, ty = tid >> 4;
    __shared__ float gs[32][64];
    __shared__ float wk[32][128];
    float acc[4][8];
#pragma unroll
    for (int i = 0; i < 4; i++)
#pragma unroll
        for (int j = 0; j < 8; j++) acc[i][j] = 0.f;

    const int k0 = kt * 128;
    for (int n0 = 0; n0 < NN; n0 += 32) {
        __syncthreads();
        {   // stage g chunk (transpose to [n][b])
            const int b = tid >> 2, ng = (tid & 3) << 3;
            float4 a = *(const float4*)(g + b * NN + n0 + ng);
            float4 c = *(const float4*)(g + b * NN + n0 + ng + 4);
            gs[ng + 0][b] = a.x; gs[ng + 1][b] = a.y; gs[ng + 2][b] = a.z; gs[ng + 3][b] = a.w;
            gs[ng + 4][b] = c.x; gs[ng + 5][b] = c.y; gs[ng + 6][b] = c.z; gs[ng + 7][b] = c.w;
        }
        {   // stage W chunk [32 n][128 k]
            const int nl = tid >> 3, off = (tid & 7) << 4;
            const float* src = W + (n0 + nl) * KTOT + k0 + off;
            float4* dst = (float4*)&wk[nl][off];
#pragma unroll
            for (int c = 0; c < 4; c++) dst[c] = ((const float4*)src)[c];
        }
        __syncthreads();
#pragma unroll
        for (int n = 0; n < 32; n++) {
            float4 gb = *(const float4*)&gs[n][ty << 2];
            float4 w0 = *(const float4*)&wk[n][tx << 3];
            float4 w1 = *(const float4*)&wk[n][(tx << 3) + 4];
            float ga[4] = {gb.x, gb.y, gb.z, gb.w};
            float wa[8] = {w0.x, w0.y, w0.z, w0.w, w1.x, w1.y, w1.z, w1.w};
#pragma unroll
            for (int i = 0; i < 4; i++)
#pragma unroll
                for (int j = 0; j < 8; j++) acc[i][j] += ga[i] * wa[j];
        }
    }
#pragma unroll
    for (int i = 0; i < 4; i++)
#pragma unroll
        for (int j = 0; j < 8; j++)
            y[(ty * 4 + i) * KTOT + k0 + tx * 8 + j] = acc[i][j];
}

// ---------------- conv(x) + y, channel softmax -> f_next ----------------
// grid (64 b, 4 row-groups of 7), block 256 (196 active positions).
__global__ __launch_bounds__(256) void conv_softmax_kernel(const float* __restrict__ x,
                                                           const float* __restrict__ wconv,
                                                           const float* __restrict__ y,
                                                           float* __restrict__ fout) {
    const int b = blockIdx.x, rg = blockIdx.y;
    const int tid = threadIdx.x;
    __shared__ float xs[CXC][11][32];   // 22528 B
    for (int lin = tid; lin < CXC * 11 * 32; lin += 256) {
        const int cx = lin / (11 * 32);
        const int rem = lin % (11 * 32);
        const int r = rem >> 5, c = rem & 31;
        xs[cx][r][c] = x[b * (CXC * LL * LL) + cx * (LL * LL) + (rg * 7 + r) * LL + c];
    }
    __syncthreads();
    if (tid < 196) {
        const int il = tid / 28, j = tid % 28;
        const int i = rg * 7 + il;
        float acc[64];
        const float* yb = y + b * KTOT + i * MM + j;
#pragma unroll
        for (int cy = 0; cy < 64; cy++) acc[cy] = yb[cy * SP];
        for (int cx = 0; cx < CXC; cx++) {
            for (int ky = 0; ky < 5; ky++) {
                float xv[5];
#pragma unroll
                for (int kx = 0; kx < 5; kx++) xv[kx] = xs[cx][il + ky][j + kx];
                const float* wb2 = wconv + cx * 25 + ky * 5;   // + cy*400
#pragma unroll
                for (int cy = 0; cy < 64; cy++) {
                    const float* wq = wb2 + cy * 400;
                    acc[cy] += xv[0] * wq[0] + xv[1] * wq[1] + xv[2] * wq[2]
                             + xv[3] * wq[3] + xv[4] * wq[4];
                }
            }
        }
        // in-register channel softmax
        float m = acc[0];
#pragma unroll
        for (int cy = 1; cy < 64; cy++) m = fmaxf(m, acc[cy]);
        float s = 0.f;
#pragma unroll
        for (int cy = 0; cy < 64; cy++) { acc[cy] = __expf(acc[cy] - m); s += acc[cy]; }
        const float inv = 1.0f / s;
        float* fo = fout + b * KTOT + i * MM + j;
#pragma unroll
        for (int cy = 0; cy < 64; cy++) fo[cy * SP] = acc[cy] * inv;
    }
}

// ---------------- x_next = 0.9*x + 0.1*convT(f_prev) ----------------
// grid (64 b, 4 row-groups of 8), block 256 (one 32x32 quarter per block).
__global__ __launch_bounds__(256) void convT_update_kernel(const float* __restrict__ f,
                                                           const float* __restrict__ wconv,
                                                           const float* __restrict__ xin,
                                                           float* __restrict__ xout) {
    const int b = blockIdx.x, rg = blockIdx.y;
    const int tid = threadIdx.x;
    const int l1 = rg * 8 + (tid >> 5), l2 = tid & 31;
    __shared__ float fs[16][12][28];   // 21504 B
    float acc[16];
#pragma unroll
    for (int cx = 0; cx < 16; cx++) acc[cx] = 0.f;

    for (int cc = 0; cc < 4; cc++) {
        __syncthreads();
        for (int lin = tid; lin < 16 * 12 * 28; lin += 256) {
            const int cyl = lin / 336;
            const int rem = lin % 336;
            const int r = rem / 28, c = rem % 28;
            const int gr = rg * 8 - 4 + r;
            float v = 0.f;
            if (gr >= 0 && gr < MM) v = f[b * KTOT + (cc * 16 + cyl) * SP + gr * MM + c];
            fs[cyl][r][c] = v;
        }
        __syncthreads();
        for (int cyl = 0; cyl < 16; cyl++) {
            for (int ky = 0; ky < 5; ky++) {
                const int lr = (tid >> 5) + 4 - ky;
                float fv[5];
#pragma unroll
                for (int kx = 0; kx < 5; kx++) {
                    const int c = l2 - kx;
                    fv[kx] = (c >= 0 && c < MM) ? fs[cyl][lr][c] : 0.f;
                }
                const float* wb2 = wconv + (cc * 16 + cyl) * 400 + ky * 5;   // + cx*25
#pragma unroll
                for (int cx = 0; cx < 16; cx++) {
                    const float* wq = wb2 + cx * 25;
                    acc[cx] += fv[0] * wq[0] + fv[1] * wq[1] + fv[2] * wq[2]
                             + fv[3] * wq[3] + fv[4] * wq[4];
                }
            }
        }
    }
    const int base = b * (CXC * LL * LL) + l1 * LL + l2;
#pragma unroll
    for (int cx = 0; cx < 16; cx++) {
        const int idx = base + cx * (LL * LL);
        xout[idx] = 0.9f * xin[idx] + 0.1f * acc[cx];
    }
}

extern "C" void kernel_launch(void* const* d_in, const int* in_sizes, int n_in,
                              void* d_out, int out_size, void* d_ws, size_t ws_size,
                              hipStream_t stream) {
    const float* x0    = (const float*)d_in[0];
    const float* f0    = (const float*)d_in[1];
    const float* wconv = (const float*)d_in[2];
    const float* W     = (const float*)d_in[3];

    float* ws = (float*)d_ws;
    const size_t XSZ = (size_t)BB * CXC * LL * LL;   // 1,048,576
    const size_t FSZ = (size_t)BB * KTOT;            // 3,211,264
    float* xb[2] = {ws, ws + XSZ};
    float* fb[2] = {ws + 2 * XSZ, ws + 2 * XSZ + FSZ};
    float* zpart = ws + 2 * XSZ + 2 * FSZ;           // 4,194,304 floats
    float* y     = zpart;                            // shared region (disjoint live ranges)
    float* g     = zpart + (size_t)64 * BB * NN;     // 65,536 floats

    hipMemcpyAsync(xb[0], x0, XSZ * sizeof(float), hipMemcpyDeviceToDevice, stream);
    hipMemcpyAsync(fb[0], f0, FSZ * sizeof(float), hipMemcpyDeviceToDevice, stream);

    for (int t = 0; t < NSTEPS; t++) {
        const int cur = t & 1, nxt = cur ^ 1;
        gemm1_kernel<<<dim3(16, 64), 256, 0, stream>>>(fb[cur], W, zpart);
        softmax_g_kernel<<<64, 256, 0, stream>>>(zpart, g);
        gemm2_kernel<<<392, 256, 0, stream>>>(g, W, y);
        conv_softmax_kernel<<<dim3(64, 4), 256, 0, stream>>>(xb[cur], wconv, y, fb[nxt]);
        convT_update_kernel<<<dim3(64, 4), 256, 0, stream>>>(fb[cur], wconv, xb[cur], xb[nxt]);
    }
    // after 50 steps (even), final state is in buffer index 0
    hipMemcpyAsync(d_out, xb[0], XSZ * sizeof(float), hipMemcpyDeviceToDevice, stream);
    hipMemcpyAsync((float*)d_out + XSZ, fb[0], FSZ * sizeof(float),
                   hipMemcpyDeviceToDevice, stream);
}

// Round 3
// 31621.033 us; speedup vs baseline: 1.3852x; 1.3852x over previous
//
#include <hip/hip_runtime.h>

#define BB 64
#define CXC 16
#define CYC 64
#define LL 32
#define MM 28
#define NN 1024
#define SP (MM*MM)          // 784
#define KTOT (CYC*SP)       // 50176
#define NSTEPS 50
#define NSPLIT 49           // 49 * 1024 = 50176

using short8  = __attribute__((ext_vector_type(8))) short;
using floatx4 = __attribute__((ext_vector_type(4))) float;

__device__ __forceinline__ ushort f2b(float v) {
    union { float f; unsigned u; } a; a.f = v;
    unsigned r = a.u + 0x7fff + ((a.u >> 16) & 1);   // round-to-nearest-even
    return (ushort)(r >> 16);
}

// ---------------- W -> bf16 (both orientations), once per call ----------------
__global__ __launch_bounds__(256) void wconvert_kernel(const float* __restrict__ W,
                                                       ushort* __restrict__ Wb,
                                                       ushort* __restrict__ WTb) {
    __shared__ float t[32][33];
    const int k0 = blockIdx.x * 32, n0 = blockIdx.y * 32;
    const int tid = threadIdx.x, r = tid >> 5, c = tid & 31;
#pragma unroll
    for (int p = 0; p < 4; p++) {
        const int rr = r + p * 8;
        const float v = W[(size_t)(n0 + rr) * KTOT + k0 + c];
        t[rr][c] = v;
        Wb[(size_t)(n0 + rr) * KTOT + k0 + c] = f2b(v);
    }
    __syncthreads();
#pragma unroll
    for (int p = 0; p < 4; p++) {
        const int rr = r + p * 8;
        WTb[(size_t)(k0 + rr) * NN + n0 + c] = f2b(t[c][rr]);   // WT[k][n] = W[n][k]
    }
}

__global__ __launch_bounds__(256) void cvt_f0_kernel(const float* __restrict__ f,
                                                     ushort* __restrict__ o) {
    const size_t i = ((size_t)blockIdx.x * 256 + threadIdx.x) * 4;
    const float4 v = *(const float4*)(f + i);
    uint2 pk;
    pk.x = (unsigned)f2b(v.x) | ((unsigned)f2b(v.y) << 16);
    pk.y = (unsigned)f2b(v.z) | ((unsigned)f2b(v.w) << 16);
    *(uint2*)(o + i) = pk;
}

// ---------------- unified bt-GEMM: C = A * B^T  (A[row][k], B[row][k], both bf16) ----
// grid (bx = 128-wide col-tiles over B rows, by = k-splits of 1024)
// block 256 = 4 waves as 2x2; wave tile 32 (A-rows) x 64 (B-rows); K staged 64/chunk.
template<int LDAB, int LDC, int CSPLIT>
__global__ __launch_bounds__(256) void gemm_bt_kernel(const ushort* __restrict__ A,
                                                      const ushort* __restrict__ B,
                                                      float* __restrict__ C) {
    const int bx = blockIdx.x, by = blockIdx.y;
    const int tid = threadIdx.x, l = tid & 63, w = tid >> 6;
    const int wr = w >> 1, wc = w & 1;
    __shared__ ushort As[4096];   //  8 KB: [rg4][kb2][ks4][r16][j8]
    __shared__ ushort Bs[8192];   // 16 KB: [rg8][kb2][ks4][r16][j8]

    floatx4 acc[2][4];
#pragma unroll
    for (int mi = 0; mi < 2; mi++)
#pragma unroll
        for (int ni = 0; ni < 4; ni++) acc[mi][ni] = (floatx4){0.f, 0.f, 0.f, 0.f};

    const size_t kbase = (size_t)by * 1024;

#pragma unroll 1
    for (int kc = 0; kc < 16; kc++) {
        const size_t koff = kbase + (size_t)kc * 64;
        __syncthreads();
        // stage A: 64 rows x 64 k  (2 chunks/thread)
#pragma unroll
        for (int i = 0; i < 2; i++) {
            const int q   = i * 256 + tid;
            const int row = ((q >> 7) << 4) | (q & 15);
            const int kk  = (((q >> 6) & 1) << 5) | (((q >> 4) & 3) << 3);
            const uint4 v = *(const uint4*)(A + (size_t)row * LDAB + koff + kk);
            *(uint4*)&As[q * 8] = v;
        }
        // stage B: 128 rows x 64 k  (4 chunks/thread)
#pragma unroll
        for (int i = 0; i < 4; i++) {
            const int q   = i * 256 + tid;
            const int row = bx * 128 + (((q >> 7) << 4) | (q & 15));
            const int kk  = (((q >> 6) & 1) << 5) | (((q >> 4) & 3) << 3);
            const uint4 v = *(const uint4*)(B + (size_t)row * LDAB + koff + kk);
            *(uint4*)&Bs[q * 8] = v;
        }
        __syncthreads();
#pragma unroll
        for (int kb = 0; kb < 2; kb++) {
            short8 a[2];
#pragma unroll
            for (int mi = 0; mi < 2; mi++)
                a[mi] = *(const short8*)&As[(wr * 2 + mi) * 1024 + kb * 512 + l * 8];
#pragma unroll
            for (int ni = 0; ni < 4; ni++) {
                const short8 b = *(const short8*)&Bs[(wc * 4 + ni) * 1024 + kb * 512 + l * 8];
                acc[0][ni] = __builtin_amdgcn_mfma_f32_16x16x32_bf16(a[0], b, acc[0][ni], 0, 0, 0);
                acc[1][ni] = __builtin_amdgcn_mfma_f32_16x16x32_bf16(a[1], b, acc[1][ni], 0, 0, 0);
            }
        }
    }
    // C write: row = wr*32 + mi*16 + (l>>4)*4 + q ; col = bx*128 + wc*64 + ni*16 + (l&15)
    float* cp = C + (size_t)by * CSPLIT + (size_t)(wr * 32 + ((l >> 4) << 2)) * LDC
              + bx * 128 + wc * 64 + (l & 15);
#pragma unroll
    for (int mi = 0; mi < 2; mi++)
#pragma unroll
        for (int ni = 0; ni < 4; ni++)
#pragma unroll
            for (int q = 0; q < 4; q++)
                cp[(size_t)(mi * 16 + q) * LDC + ni * 16] = acc[mi][ni][q];
}

// ---------------- reduce zpart over 49 splits + row softmax -> g (bf16) ----------------
__global__ __launch_bounds__(256) void softmax_g_kernel(const float* __restrict__ zpart,
                                                        ushort* __restrict__ g16) {
    const int b = blockIdx.x, tid = threadIdx.x;
    float zv[4];
#pragma unroll
    for (int q = 0; q < 4; q++) {
        const int n = tid + q * 256;
        float s = 0.f;
        for (int sp = 0; sp < NSPLIT; sp++) s += zpart[(size_t)sp * (BB * NN) + b * NN + n];
        zv[q] = s;
    }
    __shared__ float red[8];
    float m = fmaxf(fmaxf(zv[0], zv[1]), fmaxf(zv[2], zv[3]));
#pragma unroll
    for (int off = 32; off > 0; off >>= 1) m = fmaxf(m, __shfl_down(m, off));
    if ((tid & 63) == 0) red[tid >> 6] = m;
    __syncthreads();
    const float bm = fmaxf(fmaxf(red[0], red[1]), fmaxf(red[2], red[3]));
    float e[4];
    float ssum = 0.f;
#pragma unroll
    for (int q = 0; q < 4; q++) { e[q] = __expf(zv[q] - bm); ssum += e[q]; }
#pragma unroll
    for (int off = 32; off > 0; off >>= 1) ssum += __shfl_down(ssum, off);
    if ((tid & 63) == 0) red[4 + (tid >> 6)] = ssum;
    __syncthreads();
    const float inv = 1.0f / (red[4] + red[5] + red[6] + red[7]);
#pragma unroll
    for (int q = 0; q < 4; q++) g16[b * NN + tid + q * 256] = f2b(e[q] * inv);
}

// ---------------- conv(x) + y, channel softmax -> f_next (fp32 + bf16 copy) ----------------
__global__ __launch_bounds__(256) void conv_softmax_kernel(const float* __restrict__ x,
                                                           const float* __restrict__ wconv,
                                                           const float* __restrict__ y,
                                                           float* __restrict__ fout,
                                                           ushort* __restrict__ f16o) {
    const int b = blockIdx.x, rg = blockIdx.y;
    const int tid = threadIdx.x;
    __shared__ float xs[CXC][11][32];   // 22528 B
    for (int lin = tid; lin < CXC * 11 * 32; lin += 256) {
        const int cx = lin / (11 * 32);
        const int rem = lin % (11 * 32);
        const int r = rem >> 5, c = rem & 31;
        xs[cx][r][c] = x[b * (CXC * LL * LL) + cx * (LL * LL) + (rg * 7 + r) * LL + c];
    }
    __syncthreads();
    if (tid < 196) {
        const int il = tid / 28, j = tid % 28;
        const int i = rg * 7 + il;
        float acc[64];
        const float* yb = y + (size_t)b * KTOT + i * MM + j;
#pragma unroll
        for (int cy = 0; cy < 64; cy++) acc[cy] = yb[cy * SP];
        for (int cx = 0; cx < CXC; cx++) {
            for (int ky = 0; ky < 5; ky++) {
                float xv[5];
#pragma unroll
                for (int kx = 0; kx < 5; kx++) xv[kx] = xs[cx][il + ky][j + kx];
                const float* wb2 = wconv + cx * 25 + ky * 5;   // + cy*400
#pragma unroll
                for (int cy = 0; cy < 64; cy++) {
                    const float* wq = wb2 + cy * 400;
                    acc[cy] += xv[0] * wq[0] + xv[1] * wq[1] + xv[2] * wq[2]
                             + xv[3] * wq[3] + xv[4] * wq[4];
                }
            }
        }
        float m = acc[0];
#pragma unroll
        for (int cy = 1; cy < 64; cy++) m = fmaxf(m, acc[cy]);
        float s = 0.f;
#pragma unroll
        for (int cy = 0; cy < 64; cy++) { acc[cy] = __expf(acc[cy] - m); s += acc[cy]; }
        const float inv = 1.0f / s;
        float* fo = fout + (size_t)b * KTOT + i * MM + j;
        ushort* fo16 = f16o + (size_t)b * KTOT + i * MM + j;
#pragma unroll
        for (int cy = 0; cy < 64; cy++) {
            const float vv = acc[cy] * inv;
            fo[cy * SP] = vv;
            fo16[cy * SP] = f2b(vv);
        }
    }
}

// ---------------- x_next = 0.9*x + 0.1*convT(f_prev) ----------------
__global__ __launch_bounds__(256) void convT_update_kernel(const float* __restrict__ f,
                                                           const float* __restrict__ wconv,
                                                           const float* __restrict__ xin,
                                                           float* __restrict__ xout) {
    const int b = blockIdx.x, rg = blockIdx.y;
    const int tid = threadIdx.x;
    const int l1 = rg * 8 + (tid >> 5), l2 = tid & 31;
    __shared__ float fs[16][12][28];   // 21504 B
    float acc[16];
#pragma unroll
    for (int cx = 0; cx < 16; cx++) acc[cx] = 0.f;

    for (int cc = 0; cc < 4; cc++) {
        __syncthreads();
        for (int lin = tid; lin < 16 * 12 * 28; lin += 256) {
            const int cyl = lin / 336;
            const int rem = lin % 336;
            const int r = rem / 28, c = rem % 28;
            const int gr = rg * 8 - 4 + r;
            float v = 0.f;
            if (gr >= 0 && gr < MM) v = f[(size_t)b * KTOT + (cc * 16 + cyl) * SP + gr * MM + c];
            fs[cyl][r][c] = v;
        }
        __syncthreads();
        for (int cyl = 0; cyl < 16; cyl++) {
            for (int ky = 0; ky < 5; ky++) {
                const int lr = (tid >> 5) + 4 - ky;
                float fv[5];
#pragma unroll
                for (int kx = 0; kx < 5; kx++) {
                    const int c = l2 - kx;
                    fv[kx] = (c >= 0 && c < MM) ? fs[cyl][lr][c] : 0.f;
                }
                const float* wb2 = wconv + (cc * 16 + cyl) * 400 + ky * 5;   // + cx*25
#pragma unroll
                for (int cx = 0; cx < 16; cx++) {
                    const float* wq = wb2 + cx * 25;
                    acc[cx] += fv[0] * wq[0] + fv[1] * wq[1] + fv[2] * wq[2]
                             + fv[3] * wq[3] + fv[4] * wq[4];
                }
            }
        }
    }
    const int base = b * (CXC * LL * LL) + l1 * LL + l2;
#pragma unroll
    for (int cx = 0; cx < 16; cx++) {
        const int idx = base + cx * (LL * LL);
        xout[idx] = 0.9f * xin[idx] + 0.1f * acc[cx];
    }
}

extern "C" void kernel_launch(void* const* d_in, const int* in_sizes, int n_in,
                              void* d_out, int out_size, void* d_ws, size_t ws_size,
                              hipStream_t stream) {
    const float* x0    = (const float*)d_in[0];
    const float* f0    = (const float*)d_in[1];
    const float* wconv = (const float*)d_in[2];
    const float* W     = (const float*)d_in[3];

    const size_t XSZ = (size_t)BB * CXC * LL * LL;   // 1,048,576 floats
    const size_t FSZ = (size_t)BB * KTOT;            // 3,211,264 floats

    char* p = (char*)d_ws;
    ushort* Wb  = (ushort*)p;  p += (size_t)NN * KTOT * 2;     // 102,760,448
    ushort* WTb = (ushort*)p;  p += (size_t)NN * KTOT * 2;     // 102,760,448
    float*  xb0 = (float*)p;   p += XSZ * 4;
    float*  xb1 = (float*)p;   p += XSZ * 4;
    float*  fb0 = (float*)p;   p += FSZ * 4;
    float*  fb1 = (float*)p;   p += FSZ * 4;
    ushort* f16 = (ushort*)p;  p += FSZ * 2;
    float*  zy  = (float*)p;   p += (size_t)NSPLIT * BB * NN * 4;  // zpart / y alias
    ushort* g16 = (ushort*)p;  p += (size_t)BB * NN * 2;
    // total ws use: ~247.0 MiB

    float* xb[2] = {xb0, xb1};
    float* fb[2] = {fb0, fb1};

    // once-per-call conversions (deterministic)
    wconvert_kernel<<<dim3(KTOT / 32, NN / 32), 256, 0, stream>>>(W, Wb, WTb);
    cvt_f0_kernel<<<(int)(FSZ / 1024), 256, 0, stream>>>(f0, f16);
    hipMemcpyAsync(xb0, x0, XSZ * sizeof(float), hipMemcpyDeviceToDevice, stream);
    hipMemcpyAsync(fb0, f0, FSZ * sizeof(float), hipMemcpyDeviceToDevice, stream);

    for (int t = 0; t < NSTEPS; t++) {
        const int cur = t & 1, nxt = cur ^ 1;
        // GEMM1: zpart[by][b][n] = f16 @ Wb^T   (A rows = 64 b, B rows = 1024 n, K split 49x1024)
        gemm_bt_kernel<KTOT, NN, BB * NN><<<dim3(8, NSPLIT), 256, 0, stream>>>(f16, Wb, zy);
        softmax_g_kernel<<<BB, 256, 0, stream>>>(zy, g16);
        // GEMM2: y[b][kout] = g16 @ WT^T        (A rows = 64 b, B rows = 50176 kout, K = 1024)
        gemm_bt_kernel<NN, KTOT, 0><<<dim3(KTOT / 128, 1), 256, 0, stream>>>(g16, WTb, zy);
        conv_softmax_kernel<<<dim3(64, 4), 256, 0, stream>>>(xb[cur], wconv, zy, fb[nxt], f16);
        convT_update_kernel<<<dim3(64, 4), 256, 0, stream>>>(fb[cur], wconv, xb[cur], xb[nxt]);
    }
    // after 50 steps (even), final state is in buffer index 0
    hipMemcpyAsync(d_out, xb[0], XSZ * sizeof(float), hipMemcpyDeviceToDevice, stream);
    hipMemcpyAsync((float*)d_out + XSZ, fb[0], FSZ * sizeof(float),
                   hipMemcpyDeviceToDevice, stream);
}

// Round 5
// 7167.678 us; speedup vs baseline: 6.1111x; 4.4116x over previous
//
#include <hip/hip_runtime.h>

#define BB 64
#define CXC 16
#define CYC 64
#define LL 32
#define MM 28
#define NN 1024
#define SP 784
#define KTOT 50176
#define NSTEPS 50
#define NSPLIT 49

using short8  = __attribute__((ext_vector_type(8))) short;
using floatx4 = __attribute__((ext_vector_type(4))) float;

__device__ __forceinline__ ushort f2b(float v) {
    union { float f; unsigned u; } a; a.f = v;
    unsigned r = a.u + 0x7fff + ((a.u >> 16) & 1);   // RNE
    return (ushort)(r >> 16);
}
__device__ __forceinline__ unsigned pk2(float a, float b) {
    return (unsigned)f2b(a) | ((unsigned)f2b(b) << 16);
}

// ---------------- W -> bf16 (both orientations), once per call ----------------
__global__ __launch_bounds__(256) void wconvert_kernel(const float* __restrict__ W,
                                                       ushort* __restrict__ Wb,
                                                       ushort* __restrict__ WTb) {
    __shared__ float t[32][33];
    const int k0 = blockIdx.x * 32, n0 = blockIdx.y * 32;
    const int tid = threadIdx.x, r = tid >> 5, c = tid & 31;
#pragma unroll
    for (int p = 0; p < 4; p++) {
        const int rr = r + p * 8;
        const float v = W[(size_t)(n0 + rr) * KTOT + k0 + c];
        t[rr][c] = v;
        Wb[(size_t)(n0 + rr) * KTOT + k0 + c] = f2b(v);
    }
    __syncthreads();
#pragma unroll
    for (int p = 0; p < 4; p++) {
        const int rr = r + p * 8;
        WTb[(size_t)(k0 + rr) * NN + n0 + c] = f2b(t[c][rr]);
    }
}

__global__ __launch_bounds__(256) void cvt_f0_kernel(const float* __restrict__ f,
                                                     ushort* __restrict__ o) {
    const size_t i = ((size_t)blockIdx.x * 256 + threadIdx.x) * 4;
    const float4 v = *(const float4*)(f + i);
    uint2 pk; pk.x = pk2(v.x, v.y); pk.y = pk2(v.z, v.w);
    *(uint2*)(o + i) = pk;
}

// ---------------- conv-weight builders: wcA [64][416], wcT [16][1600] ----------------
__global__ __launch_bounds__(256) void wbuild_kernel(const float* __restrict__ wc,
                                                     ushort* __restrict__ wcA,
                                                     ushort* __restrict__ wcT) {
    const int bid = blockIdx.x, tid = threadIdx.x;
    if (bid < 64) {
        const int cy = bid;
        for (int k = tid; k < 416; k += 256) {
            const int tap = k >> 4, cx = k & 15;
            const float v = (tap < 25) ? wc[cy * 400 + cx * 25 + tap] : 0.f;
            wcA[cy * 416 + k] = f2b(v);
        }
    } else {
        const int cx = bid - 64;
        for (int k = tid; k < 1600; k += 256) {
            const int tap = k >> 6, cy = k & 63;
            wcT[cx * 1600 + k] = f2b(wc[cy * 400 + cx * 25 + tap]);
        }
    }
}

// ---------------- x0 std [b][cx][32][32] -> xcl fp32 [b][1024][16] + x16 bf16 ----------------
__global__ __launch_bounds__(256) void init_x_kernel(const float* __restrict__ x0,
                                                     float* __restrict__ xcl,
                                                     ushort* __restrict__ x16) {
    const int b = blockIdx.x, tid = threadIdx.x;
    __shared__ float xs[16384];
    for (int c = tid; c < 4096; c += 256)
        ((float4*)xs)[c] = ((const float4*)(x0 + (size_t)b * 16384))[c];
    __syncthreads();
    for (int p = tid; p < 1024; p += 256) {
        float v[16];
#pragma unroll
        for (int cx = 0; cx < 16; cx++) v[cx] = xs[cx * 1024 + p];
        float* dst = xcl + ((size_t)b * 1024 + p) * 16;
#pragma unroll
        for (int q = 0; q < 4; q++)
            *(float4*)(dst + q * 4) = make_float4(v[q*4], v[q*4+1], v[q*4+2], v[q*4+3]);
        uint4 u0, u1;
        u0.x = pk2(v[0], v[1]);  u0.y = pk2(v[2], v[3]);
        u0.z = pk2(v[4], v[5]);  u0.w = pk2(v[6], v[7]);
        u1.x = pk2(v[8], v[9]);  u1.y = pk2(v[10], v[11]);
        u1.z = pk2(v[12], v[13]); u1.w = pk2(v[14], v[15]);
        ushort* d16 = x16 + ((size_t)b * 1024 + p) * 16;
        *(uint4*)d16 = u0; *(uint4*)(d16 + 8) = u1;
    }
}

// ---------------- final: xcl -> d_out std [b][cx][32][32] ----------------
__global__ __launch_bounds__(256) void final_x_kernel(const float* __restrict__ xcl,
                                                      float* __restrict__ dout) {
    const int b = blockIdx.x, tid = threadIdx.x;
    __shared__ float xs[16384];
    for (int c = tid; c < 4096; c += 256)
        ((float4*)xs)[c] = ((const float4*)(xcl + (size_t)b * 16384))[c];
    __syncthreads();
    for (int idx = tid; idx < 16384; idx += 256) {
        const int cx = idx >> 10, p = idx & 1023;
        dout[(size_t)b * 16384 + idx] = xs[p * 16 + cx];
    }
}

// ---------------- f0 std -> f16pad [b][36][36][64] (halo pre-zeroed) ----------------
__global__ __launch_bounds__(256) void init_fpad_kernel(const float* __restrict__ f0,
                                                        ushort* __restrict__ fpad) {
    const int b = blockIdx.x, rg = blockIdx.y;   // rg 0..6, 112 pos each
    const int tid = threadIdx.x;
    __shared__ float fs[64 * 112];
    const float* src = f0 + (size_t)b * KTOT + rg * 112;
    for (int c = tid; c < 1792; c += 256) {
        const int cy = c / 28, p4 = (c % 28) * 4;
        *(float4*)&fs[cy * 112 + p4] = *(const float4*)(src + (size_t)cy * SP + p4);
    }
    __syncthreads();
    for (int c = tid; c < 896; c += 256) {
        const int pl = c >> 3, g8 = (c & 7) * 8;
        union { ushort u[8]; uint4 v; } pk;
#pragma unroll
        for (int e = 0; e < 8; e++) pk.u[e] = f2b(fs[(g8 + e) * 112 + pl]);
        const int pos = rg * 112 + pl, i = pos / 28, j = pos % 28;
        *(uint4*)(fpad + (((size_t)b * 36 + 4 + i) * 36 + 4 + j) * 64 + g8) = pk.v;
    }
}

// ---------------- unified bt-GEMM (unchanged from round 3) ----------------
template<int LDAB, int LDC, int CSPLIT>
__global__ __launch_bounds__(256) void gemm_bt_kernel(const ushort* __restrict__ A,
                                                      const ushort* __restrict__ B,
                                                      float* __restrict__ C) {
    const int bx = blockIdx.x, by = blockIdx.y;
    const int tid = threadIdx.x, l = tid & 63, w = tid >> 6;
    const int wr = w >> 1, wc = w & 1;
    __shared__ ushort As[4096];
    __shared__ ushort Bs[8192];

    floatx4 acc[2][4];
#pragma unroll
    for (int mi = 0; mi < 2; mi++)
#pragma unroll
        for (int ni = 0; ni < 4; ni++) acc[mi][ni] = (floatx4){0.f, 0.f, 0.f, 0.f};

    const size_t kbase = (size_t)by * 1024;

#pragma unroll 1
    for (int kc = 0; kc < 16; kc++) {
        const size_t koff = kbase + (size_t)kc * 64;
        __syncthreads();
#pragma unroll
        for (int i = 0; i < 2; i++) {
            const int q   = i * 256 + tid;
            const int row = ((q >> 7) << 4) | (q & 15);
            const int kk  = (((q >> 6) & 1) << 5) | (((q >> 4) & 3) << 3);
            const uint4 v = *(const uint4*)(A + (size_t)row * LDAB + koff + kk);
            *(uint4*)&As[q * 8] = v;
        }
#pragma unroll
        for (int i = 0; i < 4; i++) {
            const int q   = i * 256 + tid;
            const int row = bx * 128 + (((q >> 7) << 4) | (q & 15));
            const int kk  = (((q >> 6) & 1) << 5) | (((q >> 4) & 3) << 3);
            const uint4 v = *(const uint4*)(B + (size_t)row * LDAB + koff + kk);
            *(uint4*)&Bs[q * 8] = v;
        }
        __syncthreads();
#pragma unroll
        for (int kb = 0; kb < 2; kb++) {
            short8 a[2];
#pragma unroll
            for (int mi = 0; mi < 2; mi++)
                a[mi] = *(const short8*)&As[(wr * 2 + mi) * 1024 + kb * 512 + l * 8];
#pragma unroll
            for (int ni = 0; ni < 4; ni++) {
                const short8 b = *(const short8*)&Bs[(wc * 4 + ni) * 1024 + kb * 512 + l * 8];
                acc[0][ni] = __builtin_amdgcn_mfma_f32_16x16x32_bf16(a[0], b, acc[0][ni], 0, 0, 0);
                acc[1][ni] = __builtin_amdgcn_mfma_f32_16x16x32_bf16(a[1], b, acc[1][ni], 0, 0, 0);
            }
        }
    }
    float* cp = C + (size_t)by * CSPLIT + (size_t)(wr * 32 + ((l >> 4) << 2)) * LDC
              + bx * 128 + wc * 64 + (l & 15);
#pragma unroll
    for (int mi = 0; mi < 2; mi++)
#pragma unroll
        for (int ni = 0; ni < 4; ni++)
#pragma unroll
            for (int q = 0; q < 4; q++)
                cp[(size_t)(mi * 16 + q) * LDC + ni * 16] = acc[mi][ni][q];
}

// ---------------- reduce zpart + row softmax -> g (bf16), unchanged ----------------
__global__ __launch_bounds__(256) void softmax_g_kernel(const float* __restrict__ zpart,
                                                        ushort* __restrict__ g16) {
    const int b = blockIdx.x, tid = threadIdx.x;
    float zv[4];
#pragma unroll
    for (int q = 0; q < 4; q++) {
        const int n = tid + q * 256;
        float s = 0.f;
        for (int sp = 0; sp < NSPLIT; sp++) s += zpart[(size_t)sp * (BB * NN) + b * NN + n];
        zv[q] = s;
    }
    __shared__ float red[8];
    float m = fmaxf(fmaxf(zv[0], zv[1]), fmaxf(zv[2], zv[3]));
#pragma unroll
    for (int off = 32; off > 0; off >>= 1) m = fmaxf(m, __shfl_down(m, off));
    if ((tid & 63) == 0) red[tid >> 6] = m;
    __syncthreads();
    const float bm = fmaxf(fmaxf(red[0], red[1]), fmaxf(red[2], red[3]));
    float e[4];
    float ssum = 0.f;
#pragma unroll
    for (int q = 0; q < 4; q++) { e[q] = __expf(zv[q] - bm); ssum += e[q]; }
#pragma unroll
    for (int off = 32; off > 0; off >>= 1) ssum += __shfl_down(ssum, off);
    if ((tid & 63) == 0) red[4 + (tid >> 6)] = ssum;
    __syncthreads();
    const float inv = 1.0f / (red[4] + red[5] + red[6] + red[7]);
#pragma unroll
    for (int q = 0; q < 4; q++) g16[b * NN + tid + q * 256] = f2b(e[q] * inv);
}

// ---------------- MFMA conv + y + channel-softmax -> f (pad/std/f32) ----------------
// grid (64 b, 4 rg of 7 rows = 196 pos -> 13 n-frags). block 256 = 4 waves.
// A = wcA [cy][k=tap*16+cx] (M=64); B = x16 patches (N=pos); 13 K-steps of 32.
__global__ __launch_bounds__(256) void conv_mfma_kernel(const ushort* __restrict__ x16,
                                                        const ushort* __restrict__ wcA,
                                                        const float* __restrict__ y,
                                                        ushort* __restrict__ fpad,
                                                        ushort* __restrict__ fstd,
                                                        float* __restrict__ f32o) {
    const int b = blockIdx.x, rg = blockIdx.y;
    const int tid = threadIdx.x, l = tid & 63, w = tid >> 6;
    const int lr = l & 15, lg = l >> 4;
    __shared__ float yt[64 * 196];              // 50176 B; reused as ft bf16 [208][72]
    ushort* ft = (ushort*)yt;

    // stage y-tile [cy][196] (coalesced)
    {
        const float* yb = y + (size_t)b * KTOT + rg * 196;
        for (int c = tid; c < 3136; c += 256) {
            const int cy = c / 49, p4 = (c % 49) * 4;
            *(float4*)&yt[cy * 196 + p4] = *(const float4*)(yb + (size_t)cy * SP + p4);
        }
    }

    const int nf = (w == 0) ? 4 : 3;
    const int fb = (w == 0) ? 0 : (1 + 3 * w);   // frag bases 0,4,7,10

    floatx4 acc[4][4];
#pragma unroll
    for (int m = 0; m < 4; m++)
#pragma unroll
        for (int n = 0; n < 4; n++) acc[m][n] = (floatx4){0.f, 0.f, 0.f, 0.f};

    int pos_l[4], ii[4], jj[4];
#pragma unroll
    for (int n = 0; n < 4; n++) {
        int pl = (fb + n) * 16 + lr;
        if (pl > 195) pl = 195;
        pos_l[n] = pl;
        ii[n] = rg * 7 + pl / 28;
        jj[n] = pl % 28;
    }

    const int t_lane = lg >> 1;          // tap = 2s + t_lane
    const int cx0 = (lg & 1) * 8;
    const ushort* xb = x16 + ((size_t)b << 14);

    for (int s = 0; s < 13; s++) {
        short8 af[4];
#pragma unroll
        for (int m = 0; m < 4; m++)
            af[m] = *(const short8*)(wcA + (size_t)(m * 16 + lr) * 416 + s * 32 + lg * 8);
        const int tap = 2 * s + t_lane;          // <= 25 (25 = zero-padded)
        const int ky = tap / 5, kx = tap % 5;
        short8 bf[4];
#pragma unroll
        for (int n = 0; n < 4; n++) {
            if (n < nf) {
                const int pp = (ii[n] + ky) * 32 + (jj[n] + kx);
                bf[n] = *(const short8*)(xb + (size_t)pp * 16 + cx0);
            }
        }
#pragma unroll
        for (int n = 0; n < 4; n++) {
            if (n < nf) {
#pragma unroll
                for (int m = 0; m < 4; m++)
                    acc[m][n] = __builtin_amdgcn_mfma_f32_16x16x32_bf16(af[m], bf[n], acc[m][n], 0, 0, 0);
            }
        }
    }
    __syncthreads();   // y-stage visible

    // epilogue: +y, channel softmax (16 in-lane + shfl_xor 16/32), store f32 -> d_out
#pragma unroll
    for (int n = 0; n < 4; n++) {
        if (n < nf) {
            float v[16];
#pragma unroll
            for (int m = 0; m < 4; m++)
#pragma unroll
                for (int q = 0; q < 4; q++) {
                    const int cy = m * 16 + lg * 4 + q;
                    v[m * 4 + q] = acc[m][n][q] + yt[cy * 196 + pos_l[n]];
                }
            float mx = v[0];
#pragma unroll
            for (int e = 1; e < 16; e++) mx = fmaxf(mx, v[e]);
            mx = fmaxf(mx, __shfl_xor(mx, 16));
            mx = fmaxf(mx, __shfl_xor(mx, 32));
            float ss = 0.f;
#pragma unroll
            for (int e = 0; e < 16; e++) { v[e] = __expf(v[e] - mx); ss += v[e]; }
            ss += __shfl_xor(ss, 16);
            ss += __shfl_xor(ss, 32);
            const float inv = 1.0f / ss;
            const bool valid = ((fb + n) * 16 + lr) < 196;
            float* fo = f32o + (size_t)b * KTOT + rg * 196 + pos_l[n];
#pragma unroll
            for (int m = 0; m < 4; m++)
#pragma unroll
                for (int q = 0; q < 4; q++) {
                    const int cy = m * 16 + lg * 4 + q;
                    const float fv = v[m * 4 + q] * inv;
                    acc[m][n][q] = fv;                      // keep for LDS pass
                    if (valid) fo[(size_t)cy * SP] = fv;
                }
        }
    }
    __syncthreads();   // all y-reads done; LDS now reusable as ft

    // write f-tile bf16 into LDS [pos 208][cy 72-padded]
#pragma unroll
    for (int n = 0; n < 4; n++) {
        if (n < nf) {
#pragma unroll
            for (int m = 0; m < 4; m++)
#pragma unroll
                for (int q = 0; q < 4; q++)
                    ft[pos_l[n] * 72 + m * 16 + lg * 4 + q] = f2b(acc[m][n][q]);
        }
    }
    __syncthreads();

    // f16pad: [b][4+i][4+j][cy], 32B chunks
    for (int c = tid; c < 196 * 4; c += 256) {
        const int pl = c >> 2, ch = (c & 3) * 16;
        const uint4 v0 = *(const uint4*)&ft[pl * 72 + ch];
        const uint4 v1 = *(const uint4*)&ft[pl * 72 + ch + 8];
        const int gi = rg * 7 + pl / 28, gj = pl % 28;
        ushort* dst = fpad + (((size_t)b * 36 + 4 + gi) * 36 + 4 + gj) * 64 + ch;
        *(uint4*)dst = v0; *(uint4*)(dst + 8) = v1;
    }
    // f16std: [b][cy*784 + rg*196 + p]
    for (int c = tid; c < 1600; c += 256) {
        const int cy = c & 63, p8 = (c >> 6) * 8;
        if (p8 < 196) {
            union { ushort u[8]; uint4 v4; uint2 v2; } pk;
#pragma unroll
            for (int e = 0; e < 8; e++) pk.u[e] = ft[(p8 + e) * 72 + cy];
            ushort* dst = fstd + (size_t)b * KTOT + (size_t)cy * SP + rg * 196 + p8;
            if (p8 <= 188) *(uint4*)dst = pk.v4;
            else           *(uint2*)dst = pk.v2;   // tail: 4 elems
        }
    }
}

// ---------------- MFMA convT + blend: x_new = 0.9 x + 0.1 convT(f) ----------------
// grid (64 b, 4 pg of 256 pos). A = wcT [cx][k=tap*64+cy] (M=16); 50 K-steps.
__global__ __launch_bounds__(256) void convT_mfma_kernel(const ushort* __restrict__ fpad,
                                                         const ushort* __restrict__ wcT,
                                                         const float* __restrict__ xin,
                                                         float* __restrict__ xout,
                                                         ushort* __restrict__ x16o) {
    const int b = blockIdx.x, pg = blockIdx.y;
    const int tid = threadIdx.x, l = tid & 63, w = tid >> 6;
    const int lr = l & 15, lg = l >> 4;

    floatx4 acc[4];
#pragma unroll
    for (int n = 0; n < 4; n++) acc[n] = (floatx4){0.f, 0.f, 0.f, 0.f};

    int p[4], p1[4], p2[4];
#pragma unroll
    for (int n = 0; n < 4; n++) {
        p[n]  = pg * 256 + (w * 4 + n) * 16 + lr;
        p1[n] = p[n] >> 5;
        p2[n] = p[n] & 31;
    }
    const ushort* fb_b = fpad + (size_t)b * (36 * 36 * 64);
    const int cy_lo = lg * 8;

    for (int s = 0; s < 50; s++) {
        const short8 af = *(const short8*)(wcT + (size_t)lr * 1600 + s * 32 + lg * 8);
        const int tap = s >> 1;
        const int ky = tap / 5, kx = tap % 5;
        const int cy_lane = ((s & 1) << 5) + cy_lo;
        short8 bf[4];
#pragma unroll
        for (int n = 0; n < 4; n++) {
            const size_t ad = (((size_t)(p1[n] + 4 - ky)) * 36 + (p2[n] + 4 - kx)) * 64 + cy_lane;
            bf[n] = *(const short8*)(fb_b + ad);
        }
#pragma unroll
        for (int n = 0; n < 4; n++)
            acc[n] = __builtin_amdgcn_mfma_f32_16x16x32_bf16(af, bf[n], acc[n], 0, 0, 0);
    }

    // epilogue: C row = cx = lg*4+q, col = p[n]; blend + store fp32 + bf16
#pragma unroll
    for (int n = 0; n < 4; n++) {
        const size_t base = ((size_t)b * 1024 + p[n]) * 16 + lg * 4;
        const float4 xo = *(const float4*)(xin + base);
        float4 r;
        r.x = 0.9f * xo.x + 0.1f * acc[n][0];
        r.y = 0.9f * xo.y + 0.1f * acc[n][1];
        r.z = 0.9f * xo.z + 0.1f * acc[n][2];
        r.w = 0.9f * xo.w + 0.1f * acc[n][3];
        *(float4*)(xout + base) = r;
        uint2 pk; pk.x = pk2(r.x, r.y); pk.y = pk2(r.z, r.w);
        *(uint2*)(x16o + base) = pk;
    }
}

extern "C" void kernel_launch(void* const* d_in, const int* in_sizes, int n_in,
                              void* d_out, int out_size, void* d_ws, size_t ws_size,
                              hipStream_t stream) {
    const float* x0    = (const float*)d_in[0];
    const float* f0    = (const float*)d_in[1];
    const float* wconv = (const float*)d_in[2];
    const float* W     = (const float*)d_in[3];

    const size_t XSZ = (size_t)BB * CXC * LL * LL;   // 1,048,576 floats

    char* pp = (char*)d_ws;
    ushort* Wb   = (ushort*)pp; pp += (size_t)NN * KTOT * 2;        // 102,760,448
    ushort* WTb  = (ushort*)pp; pp += (size_t)NN * KTOT * 2;        // 102,760,448
    float*  xcl0 = (float*)pp;  pp += (size_t)BB * 1024 * 16 * 4;   // 4,194,304
    float*  xcl1 = (float*)pp;  pp += (size_t)BB * 1024 * 16 * 4;
    ushort* x16a = (ushort*)pp; pp += (size_t)BB * 1024 * 16 * 2;   // 2,097,152
    ushort* x16b = (ushort*)pp; pp += (size_t)BB * 1024 * 16 * 2;
    pp += 4096;                                                      // overread slack
    ushort* fpad = (ushort*)pp; pp += (size_t)BB * 36 * 36 * 64 * 2; // 10,616,832
    ushort* fstd = (ushort*)pp; pp += (size_t)BB * KTOT * 2;         // 6,422,528
    float*  zy   = (float*)pp;  pp += (size_t)NSPLIT * BB * NN * 4;  // 12,845,056
    ushort* g16  = (ushort*)pp; pp += (size_t)BB * NN * 2;           // 131,072
    ushort* wcA  = (ushort*)pp; pp += (size_t)64 * 416 * 2;          // 53,248
    ushort* wcT  = (ushort*)pp; pp += (size_t)16 * 1600 * 2;         // 51,200
    // total ~236.7 MiB (< round-3's proven 247 MiB)

    float*  xcl[2] = {xcl0, xcl1};
    ushort* x16[2] = {x16a, x16b};
    float*  f32o = (float*)d_out + XSZ;

    hipMemsetAsync(fpad, 0, (size_t)BB * 36 * 36 * 64 * 2, stream);
    hipMemsetAsync(x16a, 0, (size_t)BB * 1024 * 16 * 2 * 2 + 4096, stream);

    wconvert_kernel<<<dim3(KTOT / 32, NN / 32), 256, 0, stream>>>(W, Wb, WTb);
    wbuild_kernel<<<80, 256, 0, stream>>>(wconv, wcA, wcT);
    init_x_kernel<<<64, 256, 0, stream>>>(x0, xcl0, x16a);
    cvt_f0_kernel<<<3136, 256, 0, stream>>>(f0, fstd);
    init_fpad_kernel<<<dim3(64, 7), 256, 0, stream>>>(f0, fpad);

    for (int t = 0; t < NSTEPS; t++) {
        const int cur = t & 1, nxt = cur ^ 1;
        gemm_bt_kernel<KTOT, NN, BB * NN><<<dim3(8, NSPLIT), 256, 0, stream>>>(fstd, Wb, zy);
        softmax_g_kernel<<<BB, 256, 0, stream>>>(zy, g16);
        gemm_bt_kernel<NN, KTOT, 0><<<dim3(KTOT / 128, 1), 256, 0, stream>>>(g16, WTb, zy);
        // convT first (consumes f_t via fpad), then conv overwrites fpad/fstd with f_{t+1}
        convT_mfma_kernel<<<dim3(64, 4), 256, 0, stream>>>(fpad, wcT, xcl[cur], xcl[nxt], x16[nxt]);
        conv_mfma_kernel<<<dim3(64, 4), 256, 0, stream>>>(x16[cur], wcA, zy, fpad, fstd, f32o);
    }
    // NSTEPS=50 even -> final x state in buffer 0; f32 f already in d_out from last conv
    final_x_kernel<<<64, 256, 0, stream>>>(xcl[0], (float*)d_out);
}

// Round 6
// 5759.314 us; speedup vs baseline: 7.6055x; 1.2445x over previous
//
#include <hip/hip_runtime.h>

#define BB 64
#define CXC 16
#define CYC 64
#define LL 32
#define MM 28
#define NN 1024
#define SP 784
#define KTOT 50176
#define NSTEPS 50
#define NSPLIT 49

using short8  = __attribute__((ext_vector_type(8))) short;
using floatx4 = __attribute__((ext_vector_type(4))) float;

typedef __attribute__((address_space(1))) unsigned int gu32;
typedef __attribute__((address_space(3))) unsigned int su32;

__device__ __forceinline__ ushort f2b(float v) {
    union { float f; unsigned u; } a; a.f = v;
    unsigned r = a.u + 0x7fff + ((a.u >> 16) & 1);   // RNE
    return (ushort)(r >> 16);
}
__device__ __forceinline__ unsigned pk2(float a, float b) {
    return (unsigned)f2b(a) | ((unsigned)f2b(b) << 16);
}

// ---------------- W -> bf16 (both orientations), once per call ----------------
__global__ __launch_bounds__(256) void wconvert_kernel(const float* __restrict__ W,
                                                       ushort* __restrict__ Wb,
                                                       ushort* __restrict__ WTb) {
    __shared__ float t[32][33];
    const int k0 = blockIdx.x * 32, n0 = blockIdx.y * 32;
    const int tid = threadIdx.x, r = tid >> 5, c = tid & 31;
#pragma unroll
    for (int p = 0; p < 4; p++) {
        const int rr = r + p * 8;
        const float v = W[(size_t)(n0 + rr) * KTOT + k0 + c];
        t[rr][c] = v;
        Wb[(size_t)(n0 + rr) * KTOT + k0 + c] = f2b(v);
    }
    __syncthreads();
#pragma unroll
    for (int p = 0; p < 4; p++) {
        const int rr = r + p * 8;
        WTb[(size_t)(k0 + rr) * NN + n0 + c] = f2b(t[c][rr]);
    }
}

__global__ __launch_bounds__(256) void cvt_f0_kernel(const float* __restrict__ f,
                                                     ushort* __restrict__ o) {
    const size_t i = ((size_t)blockIdx.x * 256 + threadIdx.x) * 4;
    const float4 v = *(const float4*)(f + i);
    uint2 pk; pk.x = pk2(v.x, v.y); pk.y = pk2(v.z, v.w);
    *(uint2*)(o + i) = pk;
}

// ---------------- conv-weight builders: wcA [64][416], wcT [16][1600] ----------------
__global__ __launch_bounds__(256) void wbuild_kernel(const float* __restrict__ wc,
                                                     ushort* __restrict__ wcA,
                                                     ushort* __restrict__ wcT) {
    const int bid = blockIdx.x, tid = threadIdx.x;
    if (bid < 64) {
        const int cy = bid;
        for (int k = tid; k < 416; k += 256) {
            const int tap = k >> 4, cx = k & 15;
            const float v = (tap < 25) ? wc[cy * 400 + cx * 25 + tap] : 0.f;
            wcA[cy * 416 + k] = f2b(v);
        }
    } else {
        const int cx = bid - 64;
        for (int k = tid; k < 1600; k += 256) {
            const int tap = k >> 6, cy = k & 63;
            wcT[cx * 1600 + k] = f2b(wc[cy * 400 + cx * 25 + tap]);
        }
    }
}

// ---------------- x0 std [b][cx][32][32] -> xcl fp32 [b][1024][16] + x16 bf16 ----------------
__global__ __launch_bounds__(256) void init_x_kernel(const float* __restrict__ x0,
                                                     float* __restrict__ xcl,
                                                     ushort* __restrict__ x16) {
    const int b = blockIdx.x, tid = threadIdx.x;
    __shared__ float xs[16384];
    for (int c = tid; c < 4096; c += 256)
        ((float4*)xs)[c] = ((const float4*)(x0 + (size_t)b * 16384))[c];
    __syncthreads();
    for (int p = tid; p < 1024; p += 256) {
        float v[16];
#pragma unroll
        for (int cx = 0; cx < 16; cx++) v[cx] = xs[cx * 1024 + p];
        float* dst = xcl + ((size_t)b * 1024 + p) * 16;
#pragma unroll
        for (int q = 0; q < 4; q++)
            *(float4*)(dst + q * 4) = make_float4(v[q*4], v[q*4+1], v[q*4+2], v[q*4+3]);
        uint4 u0, u1;
        u0.x = pk2(v[0], v[1]);  u0.y = pk2(v[2], v[3]);
        u0.z = pk2(v[4], v[5]);  u0.w = pk2(v[6], v[7]);
        u1.x = pk2(v[8], v[9]);  u1.y = pk2(v[10], v[11]);
        u1.z = pk2(v[12], v[13]); u1.w = pk2(v[14], v[15]);
        ushort* d16 = x16 + ((size_t)b * 1024 + p) * 16;
        *(uint4*)d16 = u0; *(uint4*)(d16 + 8) = u1;
    }
}

// ---------------- final: xcl -> d_out std [b][cx][32][32] ----------------
__global__ __launch_bounds__(256) void final_x_kernel(const float* __restrict__ xcl,
                                                      float* __restrict__ dout) {
    const int b = blockIdx.x, tid = threadIdx.x;
    __shared__ float xs[16384];
    for (int c = tid; c < 4096; c += 256)
        ((float4*)xs)[c] = ((const float4*)(xcl + (size_t)b * 16384))[c];
    __syncthreads();
    for (int idx = tid; idx < 16384; idx += 256) {
        const int cx = idx >> 10, p = idx & 1023;
        dout[(size_t)b * 16384 + idx] = xs[p * 16 + cx];
    }
}

// ---------------- f0 std -> f16pad [b][36][36][64] (halo pre-zeroed) ----------------
__global__ __launch_bounds__(256) void init_fpad_kernel(const float* __restrict__ f0,
                                                        ushort* __restrict__ fpad) {
    const int b = blockIdx.x, rg = blockIdx.y;   // rg 0..6, 112 pos each
    const int tid = threadIdx.x;
    __shared__ float fs[64 * 112];
    const float* src = f0 + (size_t)b * KTOT + rg * 112;
    for (int c = tid; c < 1792; c += 256) {
        const int cy = c / 28, p4 = (c % 28) * 4;
        *(float4*)&fs[cy * 112 + p4] = *(const float4*)(src + (size_t)cy * SP + p4);
    }
    __syncthreads();
    for (int c = tid; c < 896; c += 256) {
        const int pl = c >> 3, g8 = (c & 7) * 8;
        union { ushort u[8]; uint4 v; } pk;
#pragma unroll
        for (int e = 0; e < 8; e++) pk.u[e] = f2b(fs[(g8 + e) * 112 + pl]);
        const int pos = rg * 112 + pl, i = pos / 28, j = pos % 28;
        *(uint4*)(fpad + (((size_t)b * 36 + 4 + i) * 36 + 4 + j) * 64 + g8) = pk.v;
    }
}

// ---------------- pipelined bt-GEMM: C = A * B^T (both bf16, [row][k]) ----------------
// 2-phase global_load_lds pipeline: stage tile t+1 while computing tile t.
// Counted vmcnt(6) -> prefetch loads stay in flight across the barrier (T3+T4 min form).
// block 256 = 4 waves 2x2; tile 64(A-rows) x 128(B-rows); K-chunk 64, 16 chunks.
template<int LDAB, int LDC, int CSPLIT>
__global__ __launch_bounds__(256, 3) void gemm_bt_kernel(const ushort* __restrict__ A,
                                                         const ushort* __restrict__ B,
                                                         float* __restrict__ C) {
    const int bx = blockIdx.x, by = blockIdx.y;
    const int tid = threadIdx.x, l = tid & 63, w = tid >> 6;
    const int wr = w >> 1, wc = w & 1;
    __shared__ __attribute__((aligned(16))) ushort As[2][4096];   // 2 x 8 KB
    __shared__ __attribute__((aligned(16))) ushort Bs[2][8192];   // 2 x 16 KB

    floatx4 acc[2][4];
#pragma unroll
    for (int mi = 0; mi < 2; mi++)
#pragma unroll
        for (int ni = 0; ni < 4; ni++) acc[mi][ni] = (floatx4){0.f, 0.f, 0.f, 0.f};

    const size_t kbase = (size_t)by * 1024;

    auto STAGE = [&](int buf, int kc) {
        const size_t koff = kbase + (size_t)kc * 64;
#pragma unroll
        for (int i = 0; i < 2; i++) {          // A: 64 rows x 64 k
            const int q   = i * 256 + tid;
            const int row = ((q >> 7) << 4) | (q & 15);
            const int kk  = (((q >> 6) & 1) << 5) | (((q >> 4) & 3) << 3);
            __builtin_amdgcn_global_load_lds((gu32*)(A + (size_t)row * LDAB + koff + kk),
                                             (su32*)&As[buf][q * 8], 16, 0, 0);
        }
#pragma unroll
        for (int i = 0; i < 4; i++) {          // B: 128 rows x 64 k
            const int q   = i * 256 + tid;
            const int row = bx * 128 + (((q >> 7) << 4) | (q & 15));
            const int kk  = (((q >> 6) & 1) << 5) | (((q >> 4) & 3) << 3);
            __builtin_amdgcn_global_load_lds((gu32*)(B + (size_t)row * LDAB + koff + kk),
                                             (su32*)&Bs[buf][q * 8], 16, 0, 0);
        }
    };

    STAGE(0, 0);                                // 6 loads in flight
#pragma unroll 1
    for (int kc = 0; kc < 16; kc++) {
        const int cur = kc & 1;
        if (kc < 15) {
            STAGE(cur ^ 1, kc + 1);             // +6 -> 12 in flight
            asm volatile("s_waitcnt vmcnt(6)" ::: "memory");   // tile kc landed; kc+1 stays in flight
        } else {
            asm volatile("s_waitcnt vmcnt(0)" ::: "memory");
        }
        __builtin_amdgcn_s_barrier();           // all waves' stage-writes visible
#pragma unroll
        for (int kb = 0; kb < 2; kb++) {
            short8 a[2];
#pragma unroll
            for (int mi = 0; mi < 2; mi++)
                a[mi] = *(const short8*)&As[cur][(wr * 2 + mi) * 1024 + kb * 512 + l * 8];
#pragma unroll
            for (int ni = 0; ni < 4; ni++) {
                const short8 b = *(const short8*)&Bs[cur][(wc * 4 + ni) * 1024 + kb * 512 + l * 8];
                acc[0][ni] = __builtin_amdgcn_mfma_f32_16x16x32_bf16(a[0], b, acc[0][ni], 0, 0, 0);
                acc[1][ni] = __builtin_amdgcn_mfma_f32_16x16x32_bf16(a[1], b, acc[1][ni], 0, 0, 0);
            }
        }
        __builtin_amdgcn_s_barrier();           // reads done before next overwrite of this buf
    }
    float* cp = C + (size_t)by * CSPLIT + (size_t)(wr * 32 + ((l >> 4) << 2)) * LDC
              + bx * 128 + wc * 64 + (l & 15);
#pragma unroll
    for (int mi = 0; mi < 2; mi++)
#pragma unroll
        for (int ni = 0; ni < 4; ni++)
#pragma unroll
            for (int q = 0; q < 4; q++)
                cp[(size_t)(mi * 16 + q) * LDC + ni * 16] = acc[mi][ni][q];
}

// ---------------- zpart reduce (full machine) then row softmax -> g ----------------
__global__ __launch_bounds__(256) void reduce_z_kernel(const float* __restrict__ zpart,
                                                       float* __restrict__ z) {
    const int b = blockIdx.x;
    const int n = blockIdx.y * 256 + threadIdx.x;
    float s = 0.f;
    for (int sp = 0; sp < NSPLIT; sp++) s += zpart[(size_t)sp * (BB * NN) + b * NN + n];
    z[b * NN + n] = s;
}

__global__ __launch_bounds__(256) void softmax_z_kernel(const float* __restrict__ z,
                                                        ushort* __restrict__ g16) {
    const int b = blockIdx.x, tid = threadIdx.x;
    float zv[4];
#pragma unroll
    for (int q = 0; q < 4; q++) zv[q] = z[b * NN + tid + q * 256];
    __shared__ float red[8];
    float m = fmaxf(fmaxf(zv[0], zv[1]), fmaxf(zv[2], zv[3]));
#pragma unroll
    for (int off = 32; off > 0; off >>= 1) m = fmaxf(m, __shfl_down(m, off));
    if ((tid & 63) == 0) red[tid >> 6] = m;
    __syncthreads();
    const float bm = fmaxf(fmaxf(red[0], red[1]), fmaxf(red[2], red[3]));
    float e[4];
    float ssum = 0.f;
#pragma unroll
    for (int q = 0; q < 4; q++) { e[q] = __expf(zv[q] - bm); ssum += e[q]; }
#pragma unroll
    for (int off = 32; off > 0; off >>= 1) ssum += __shfl_down(ssum, off);
    if ((tid & 63) == 0) red[4 + (tid >> 6)] = ssum;
    __syncthreads();
    const float inv = 1.0f / (red[4] + red[5] + red[6] + red[7]);
#pragma unroll
    for (int q = 0; q < 4; q++) g16[b * NN + tid + q * 256] = f2b(e[q] * inv);
}

// ---------------- MFMA conv + y + channel-softmax -> f (pad/std/f32) ----------------
__global__ __launch_bounds__(256) void conv_mfma_kernel(const ushort* __restrict__ x16,
                                                        const ushort* __restrict__ wcA,
                                                        const float* __restrict__ y,
                                                        ushort* __restrict__ fpad,
                                                        ushort* __restrict__ fstd,
                                                        float* __restrict__ f32o) {
    const int b = blockIdx.x, rg = blockIdx.y;
    const int tid = threadIdx.x, l = tid & 63, w = tid >> 6;
    const int lr = l & 15, lg = l >> 4;
    __shared__ float yt[64 * 196];              // 50176 B; reused as ft bf16 [208][72]
    ushort* ft = (ushort*)yt;

    {
        const float* yb = y + (size_t)b * KTOT + rg * 196;
        for (int c = tid; c < 3136; c += 256) {
            const int cy = c / 49, p4 = (c % 49) * 4;
            *(float4*)&yt[cy * 196 + p4] = *(const float4*)(yb + (size_t)cy * SP + p4);
        }
    }

    const int nf = (w == 0) ? 4 : 3;
    const int fb = (w == 0) ? 0 : (1 + 3 * w);   // frag bases 0,4,7,10

    floatx4 acc[4][4];
#pragma unroll
    for (int m = 0; m < 4; m++)
#pragma unroll
        for (int n = 0; n < 4; n++) acc[m][n] = (floatx4){0.f, 0.f, 0.f, 0.f};

    int pos_l[4], ii[4], jj[4];
#pragma unroll
    for (int n = 0; n < 4; n++) {
        int pl = (fb + n) * 16 + lr;
        if (pl > 195) pl = 195;
        pos_l[n] = pl;
        ii[n] = rg * 7 + pl / 28;
        jj[n] = pl % 28;
    }

    const int t_lane = lg >> 1;
    const int cx0 = (lg & 1) * 8;
    const ushort* xb = x16 + ((size_t)b << 14);

    for (int s = 0; s < 13; s++) {
        short8 af[4];
#pragma unroll
        for (int m = 0; m < 4; m++)
            af[m] = *(const short8*)(wcA + (size_t)(m * 16 + lr) * 416 + s * 32 + lg * 8);
        const int tap = 2 * s + t_lane;
        const int ky = tap / 5, kx = tap % 5;
        short8 bf[4];
#pragma unroll
        for (int n = 0; n < 4; n++) {
            if (n < nf) {
                const int pp = (ii[n] + ky) * 32 + (jj[n] + kx);
                bf[n] = *(const short8*)(xb + (size_t)pp * 16 + cx0);
            }
        }
#pragma unroll
        for (int n = 0; n < 4; n++) {
            if (n < nf) {
#pragma unroll
                for (int m = 0; m < 4; m++)
                    acc[m][n] = __builtin_amdgcn_mfma_f32_16x16x32_bf16(af[m], bf[n], acc[m][n], 0, 0, 0);
            }
        }
    }
    __syncthreads();   // y-stage visible

#pragma unroll
    for (int n = 0; n < 4; n++) {
        if (n < nf) {
            float v[16];
#pragma unroll
            for (int m = 0; m < 4; m++)
#pragma unroll
                for (int q = 0; q < 4; q++) {
                    const int cy = m * 16 + lg * 4 + q;
                    v[m * 4 + q] = acc[m][n][q] + yt[cy * 196 + pos_l[n]];
                }
            float mx = v[0];
#pragma unroll
            for (int e = 1; e < 16; e++) mx = fmaxf(mx, v[e]);
            mx = fmaxf(mx, __shfl_xor(mx, 16));
            mx = fmaxf(mx, __shfl_xor(mx, 32));
            float ss = 0.f;
#pragma unroll
            for (int e = 0; e < 16; e++) { v[e] = __expf(v[e] - mx); ss += v[e]; }
            ss += __shfl_xor(ss, 16);
            ss += __shfl_xor(ss, 32);
            const float inv = 1.0f / ss;
            const bool valid = ((fb + n) * 16 + lr) < 196;
            float* fo = f32o + (size_t)b * KTOT + rg * 196 + pos_l[n];
#pragma unroll
            for (int m = 0; m < 4; m++)
#pragma unroll
                for (int q = 0; q < 4; q++) {
                    const int cy = m * 16 + lg * 4 + q;
                    const float fv = v[m * 4 + q] * inv;
                    acc[m][n][q] = fv;
                    if (valid) fo[(size_t)cy * SP] = fv;
                }
        }
    }
    __syncthreads();   // all y-reads done; LDS reusable as ft

#pragma unroll
    for (int n = 0; n < 4; n++) {
        if (n < nf) {
#pragma unroll
            for (int m = 0; m < 4; m++)
#pragma unroll
                for (int q = 0; q < 4; q++)
                    ft[pos_l[n] * 72 + m * 16 + lg * 4 + q] = f2b(acc[m][n][q]);
        }
    }
    __syncthreads();

    for (int c = tid; c < 196 * 4; c += 256) {
        const int pl = c >> 2, ch = (c & 3) * 16;
        const uint4 v0 = *(const uint4*)&ft[pl * 72 + ch];
        const uint4 v1 = *(const uint4*)&ft[pl * 72 + ch + 8];
        const int gi = rg * 7 + pl / 28, gj = pl % 28;
        ushort* dst = fpad + (((size_t)b * 36 + 4 + gi) * 36 + 4 + gj) * 64 + ch;
        *(uint4*)dst = v0; *(uint4*)(dst + 8) = v1;
    }
    for (int c = tid; c < 1600; c += 256) {
        const int cy = c & 63, p8 = (c >> 6) * 8;
        if (p8 < 196) {
            union { ushort u[8]; uint4 v4; uint2 v2; } pk;
#pragma unroll
            for (int e = 0; e < 8; e++) pk.u[e] = ft[(p8 + e) * 72 + cy];
            ushort* dst = fstd + (size_t)b * KTOT + (size_t)cy * SP + rg * 196 + p8;
            if (p8 <= 188) *(uint4*)dst = pk.v4;
            else           *(uint2*)dst = pk.v2;
        }
    }
}

// ---------------- MFMA convT + blend: x_new = 0.9 x + 0.1 convT(f) ----------------
__global__ __launch_bounds__(256) void convT_mfma_kernel(const ushort* __restrict__ fpad,
                                                         const ushort* __restrict__ wcT,
                                                         const float* __restrict__ xin,
                                                         float* __restrict__ xout,
                                                         ushort* __restrict__ x16o) {
    const int b = blockIdx.x, pg = blockIdx.y;
    const int tid = threadIdx.x, l = tid & 63, w = tid >> 6;
    const int lr = l & 15, lg = l >> 4;

    floatx4 acc[4];
#pragma unroll
    for (int n = 0; n < 4; n++) acc[n] = (floatx4){0.f, 0.f, 0.f, 0.f};

    int p[4], p1[4], p2[4];
#pragma unroll
    for (int n = 0; n < 4; n++) {
        p[n]  = pg * 256 + (w * 4 + n) * 16 + lr;
        p1[n] = p[n] >> 5;
        p2[n] = p[n] & 31;
    }
    const ushort* fb_b = fpad + (size_t)b * (36 * 36 * 64);
    const int cy_lo = lg * 8;

    for (int s = 0; s < 50; s++) {
        const short8 af = *(const short8*)(wcT + (size_t)lr * 1600 + s * 32 + lg * 8);
        const int tap = s >> 1;
        const int ky = tap / 5, kx = tap % 5;
        const int cy_lane = ((s & 1) << 5) + cy_lo;
        short8 bf[4];
#pragma unroll
        for (int n = 0; n < 4; n++) {
            const size_t ad = (((size_t)(p1[n] + 4 - ky)) * 36 + (p2[n] + 4 - kx)) * 64 + cy_lane;
            bf[n] = *(const short8*)(fb_b + ad);
        }
#pragma unroll
        for (int n = 0; n < 4; n++)
            acc[n] = __builtin_amdgcn_mfma_f32_16x16x32_bf16(af, bf[n], acc[n], 0, 0, 0);
    }

#pragma unroll
    for (int n = 0; n < 4; n++) {
        const size_t base = ((size_t)b * 1024 + p[n]) * 16 + lg * 4;
        const float4 xo = *(const float4*)(xin + base);
        float4 r;
        r.x = 0.9f * xo.x + 0.1f * acc[n][0];
        r.y = 0.9f * xo.y + 0.1f * acc[n][1];
        r.z = 0.9f * xo.z + 0.1f * acc[n][2];
        r.w = 0.9f * xo.w + 0.1f * acc[n][3];
        *(float4*)(xout + base) = r;
        uint2 pk; pk.x = pk2(r.x, r.y); pk.y = pk2(r.z, r.w);
        *(uint2*)(x16o + base) = pk;
    }
}

extern "C" void kernel_launch(void* const* d_in, const int* in_sizes, int n_in,
                              void* d_out, int out_size, void* d_ws, size_t ws_size,
                              hipStream_t stream) {
    const float* x0    = (const float*)d_in[0];
    const float* f0    = (const float*)d_in[1];
    const float* wconv = (const float*)d_in[2];
    const float* W     = (const float*)d_in[3];

    const size_t XSZ = (size_t)BB * CXC * LL * LL;   // 1,048,576 floats

    char* pp = (char*)d_ws;
    ushort* Wb   = (ushort*)pp; pp += (size_t)NN * KTOT * 2;        // 102,760,448
    ushort* WTb  = (ushort*)pp; pp += (size_t)NN * KTOT * 2;        // 102,760,448
    float*  xcl0 = (float*)pp;  pp += (size_t)BB * 1024 * 16 * 4;   // 4,194,304
    float*  xcl1 = (float*)pp;  pp += (size_t)BB * 1024 * 16 * 4;
    ushort* x16a = (ushort*)pp; pp += (size_t)BB * 1024 * 16 * 2;   // 2,097,152
    ushort* x16b = (ushort*)pp; pp += (size_t)BB * 1024 * 16 * 2;
    pp += 4096;                                                      // overread slack
    ushort* fpad = (ushort*)pp; pp += (size_t)BB * 36 * 36 * 64 * 2; // 10,616,832
    ushort* fstd = (ushort*)pp; pp += (size_t)BB * KTOT * 2;         // 6,422,528
    float*  zy   = (float*)pp;  pp += (size_t)NSPLIT * BB * NN * 4;  // 12,845,056
    float*  zred = (float*)pp;  pp += (size_t)BB * NN * 4;           // 262,144
    ushort* g16  = (ushort*)pp; pp += (size_t)BB * NN * 2;           // 131,072
    ushort* wcA  = (ushort*)pp; pp += (size_t)64 * 416 * 2;          // 53,248
    ushort* wcT  = (ushort*)pp; pp += (size_t)16 * 1600 * 2;         // 51,200
    // total ~237 MiB (< round-3's proven 247 MiB)

    float*  xcl[2] = {xcl0, xcl1};
    ushort* x16[2] = {x16a, x16b};
    float*  f32o = (float*)d_out + XSZ;

    hipMemsetAsync(fpad, 0, (size_t)BB * 36 * 36 * 64 * 2, stream);
    hipMemsetAsync(x16a, 0, (size_t)BB * 1024 * 16 * 2 * 2 + 4096, stream);

    wconvert_kernel<<<dim3(KTOT / 32, NN / 32), 256, 0, stream>>>(W, Wb, WTb);
    wbuild_kernel<<<80, 256, 0, stream>>>(wconv, wcA, wcT);
    init_x_kernel<<<64, 256, 0, stream>>>(x0, xcl0, x16a);
    cvt_f0_kernel<<<3136, 256, 0, stream>>>(f0, fstd);
    init_fpad_kernel<<<dim3(64, 7), 256, 0, stream>>>(f0, fpad);

    for (int t = 0; t < NSTEPS; t++) {
        const int cur = t & 1, nxt = cur ^ 1;
        gemm_bt_kernel<KTOT, NN, BB * NN><<<dim3(8, NSPLIT), 256, 0, stream>>>(fstd, Wb, zy);
        reduce_z_kernel<<<dim3(BB, 4), 256, 0, stream>>>(zy, zred);
        softmax_z_kernel<<<BB, 256, 0, stream>>>(zred, g16);
        gemm_bt_kernel<NN, KTOT, 0><<<dim3(KTOT / 128, 1), 256, 0, stream>>>(g16, WTb, zy);
        convT_mfma_kernel<<<dim3(64, 4), 256, 0, stream>>>(fpad, wcT, xcl[cur], xcl[nxt], x16[nxt]);
        conv_mfma_kernel<<<dim3(64, 4), 256, 0, stream>>>(x16[cur], wcA, zy, fpad, fstd, f32o);
    }
    final_x_kernel<<<64, 256, 0, stream>>>(xcl[0], (float*)d_out);
}